// Round 1
// baseline (1312.704 us; speedup 1.0000x reference)
//
#include <hip/hip_runtime.h>

// Problem constants (N,C,H,W) = (8,19,384,384)
#define NCLS 19
#define HW   147456            // 384*384
#define MPIX 1179648           // 8*384*384
#define NB   32768             // histogram buckets per class
#define TB   256               // scan block threads
#define CHUNK (NB / TB)        // 128 buckets per thread

__global__ void softmax_err_hist(const float* __restrict__ logits,
                                 const int* __restrict__ label,
                                 float* __restrict__ errs,        // [C, M]
                                 unsigned int* __restrict__ cnt,  // [C, NB]
                                 unsigned int* __restrict__ pos)  // [C, NB]
{
    int m = blockIdx.x * blockDim.x + threadIdx.x;
    if (m >= MPIX) return;
    int n = m / HW;
    int base = m + n * (NCLS - 1) * HW;   // == (n*C)*HW + (m - n*HW)

    float v[NCLS];
    float mx = -1e30f;
#pragma unroll
    for (int c = 0; c < NCLS; ++c) {
        float x = logits[base + c * HW];
        v[c] = x;
        mx = fmaxf(mx, x);
    }
    float s = 0.f;
#pragma unroll
    for (int c = 0; c < NCLS; ++c) {
        float e = __expf(v[c] - mx);
        v[c] = e;
        s += e;
    }
    float inv = 1.0f / s;
    int lbl = label[m];
#pragma unroll
    for (int c = 0; c < NCLS; ++c) {
        float p = v[c] * inv;
        float err = (c == lbl) ? (1.0f - p) : p;
        errs[c * MPIX + m] = err;
        int k = (int)(err * (float)NB);
        k = min(k, NB - 1);
        k = max(k, 0);
        atomicAdd(&cnt[c * NB + k], 1u);
        if (c == lbl) atomicAdd(&pos[c * NB + k], 1u);
    }
}

__device__ __forceinline__ double jaccval(unsigned int n, unsigned int p, unsigned int npos)
{
    // J = 1 - (npos - p) / (npos + n - p); define 0/0 -> 0
    unsigned int denom = (npos - p) + n;
    if (denom == 0u) return 0.0;
    return 1.0 - (double)(npos - p) / (double)denom;
}

__global__ void lovasz_scan(const unsigned int* __restrict__ cnt,
                            const unsigned int* __restrict__ pos,
                            float* __restrict__ out0)
{
    int c = blockIdx.x;
    const unsigned int* cc = cnt + c * NB;
    const unsigned int* pp = pos + c * NB;
    int t = threadIdx.x;
    int lo = t * CHUNK;

    // pass 1: per-thread chunk sums
    unsigned int sc = 0, sp = 0;
    for (int k = lo; k < lo + CHUNK; ++k) { sc += cc[k]; sp += pp[k]; }

    __shared__ unsigned int sc_[TB], sp_[TB];
    sc_[t] = sc; sp_[t] = sp;
    __syncthreads();

    // suffix-exclusive (buckets above my chunk) + total positives
    unsigned int N = 0, P = 0, totP = 0;
    for (int u = 0; u < TB; ++u) {
        totP += sp_[u];
        if (u > t) { N += sc_[u]; P += sp_[u]; }
    }

    // pass 2: walk my chunk from the top (high err -> low err), trapezoid integrate
    double acc = 0.0;
    double Jprev = jaccval(N, P, totP);
    for (int k = lo + CHUNK - 1; k >= lo; --k) {
        N += cc[k]; P += pp[k];
        double Jnew = jaccval(N, P, totP);
        acc += 0.5 * (Jprev + Jnew);
        Jprev = Jnew;
    }

    __shared__ double red[TB];
    red[t] = acc;
    __syncthreads();
    for (int s2 = TB / 2; s2 > 0; s2 >>= 1) {
        if (t < s2) red[t] += red[t + s2];
        __syncthreads();
    }
    if (t == 0) {
        double loss_c = red[0] / (double)NB;   // times bucket width 1/NB
        atomicAdd(out0, (float)(loss_c / (double)NCLS));
    }
}

extern "C" void kernel_launch(void* const* d_in, const int* in_sizes, int n_in,
                              void* d_out, int out_size, void* d_ws, size_t ws_size,
                              hipStream_t stream)
{
    const float* logits = (const float*)d_in[0];
    const int*   label  = (const int*)d_in[1];
    float* out = (float*)d_out;

    unsigned int* cnt = (unsigned int*)d_ws;
    unsigned int* pos = cnt + (size_t)NCLS * NB;

    // zero histograms and the scalar output slot (capture-safe async memsets)
    hipMemsetAsync(d_ws, 0, (size_t)2 * NCLS * NB * sizeof(unsigned int), stream);
    hipMemsetAsync(d_out, 0, sizeof(float), stream);

    dim3 block(256);
    dim3 grid((MPIX + 255) / 256);
    softmax_err_hist<<<grid, block, 0, stream>>>(logits, label, out + 1, cnt, pos);
    lovasz_scan<<<NCLS, TB, 0, stream>>>(cnt, pos, out);
}

// Round 2
// 276.629 us; speedup vs baseline: 4.7454x; 4.7454x over previous
//
#include <hip/hip_runtime.h>

// Problem constants (N,C,H,W) = (8,19,384,384)
#define NCLS 19
#define HW   147456            // 384*384
#define MPIX 1179648           // 8*384*384
#define NB   512               // histogram buckets per class (LDS-resident)
#define TPB  256
#define HSZ  (NCLS * NB)       // 9728 packed u32 words per block histogram

// Kernel A: per-pixel softmax -> errs output + per-block LDS histogram.
// hist[c][k] packs cnt in low 16 bits, pos in high 16 bits (per-block pixel
// count <= MPIX/nblk <= 65535 for nblk >= 19, so no overflow).
__global__ void __launch_bounds__(TPB) softmax_err_hist(
    const float* __restrict__ logits,
    const int* __restrict__ label,
    float* __restrict__ errs,              // [C, M]
    unsigned int* __restrict__ partial,    // [nblk][HSZ]
    int nblk)
{
    __shared__ unsigned int hist[HSZ];     // 38,912 B -> 4 blocks/CU
    const int tid = threadIdx.x;
    const int b = blockIdx.x;

    for (int i = tid; i < HSZ; i += TPB) hist[i] = 0u;
    __syncthreads();

    for (int m = b * TPB + tid; m < MPIX; m += nblk * TPB) {
        int n = m / HW;
        int base = m + n * (NCLS - 1) * HW;     // == n*C*HW + (m - n*HW)

        float v[NCLS];
        float mx = -1e30f;
#pragma unroll
        for (int c = 0; c < NCLS; ++c) {
            float x = logits[base + c * HW];
            v[c] = x;
            mx = fmaxf(mx, x);
        }
        float s = 0.f;
#pragma unroll
        for (int c = 0; c < NCLS; ++c) {
            float e = __expf(v[c] - mx);
            v[c] = e;
            s += e;
        }
        float inv = 1.0f / s;
        int lbl = label[m];
#pragma unroll
        for (int c = 0; c < NCLS; ++c) {
            float p = v[c] * inv;
            float err = (c == lbl) ? (1.0f - p) : p;
            errs[c * MPIX + m] = err;
            int k = (int)(err * (float)NB);
            k = min(k, NB - 1);
            k = max(k, 0);
            unsigned int add = 1u + ((c == lbl) ? 65536u : 0u);
            atomicAdd(&hist[c * NB + k], add);
        }
    }
    __syncthreads();

    // non-atomic coalesced flush to this block's private slice
    unsigned int* dst = partial + (size_t)b * HSZ;
    for (int i = tid; i < HSZ; i += TPB) dst[i] = hist[i];
}

__device__ __forceinline__ double jaccval(unsigned int n, unsigned int p, unsigned int npos)
{
    // J = 1 - (npos - p) / (npos + n - p); define 0/0 -> 0
    unsigned int denom = (npos - p) + n;
    if (denom == 0u) return 0.0;
    return 1.0 - (double)(npos - p) / (double)denom;
}

// Kernel B: one block per class. Reduce the nblk partial histograms
// (unpack u16 pairs before summing), then suffix-scan + trapezoid integrate.
__global__ void __launch_bounds__(TPB) lovasz_scan(
    const unsigned int* __restrict__ partial,   // [nblk][HSZ]
    int nblk,
    float* __restrict__ out0)
{
    const int c = blockIdx.x;
    const int t = threadIdx.x;

    __shared__ unsigned int cntS[NB], posS[NB];

    // thread t reduces buckets t and t+256 across all partial blocks
    unsigned int c0 = 0, p0 = 0, c1 = 0, p1 = 0;
    for (int b = 0; b < nblk; ++b) {
        const unsigned int* row = partial + (size_t)b * HSZ + c * NB;
        unsigned int w0 = row[t];
        unsigned int w1 = row[t + 256];
        c0 += w0 & 0xFFFFu; p0 += w0 >> 16;
        c1 += w1 & 0xFFFFu; p1 += w1 >> 16;
    }
    cntS[t] = c0;       posS[t] = p0;
    cntS[t + 256] = c1; posS[t + 256] = p1;
    __syncthreads();

    // per-thread chunk (2 buckets: 2t, 2t+1) sums
    unsigned int sc = cntS[2 * t] + cntS[2 * t + 1];
    unsigned int sp = posS[2 * t] + posS[2 * t + 1];

    __shared__ unsigned int scS[TPB], spS[TPB];
    scS[t] = sc; spS[t] = sp;
    __syncthreads();

    // suffix-exclusive counts (buckets above my chunk) + total positives
    unsigned int N = 0, P = 0, totP = 0;
    for (int u = 0; u < TPB; ++u) {
        totP += spS[u];
        if (u > t) { N += scS[u]; P += spS[u]; }
    }

    // walk my 2 buckets from the top, trapezoid integrate
    double acc = 0.0;
    double Jprev = jaccval(N, P, totP);
    for (int k = 2 * t + 1; k >= 2 * t; --k) {
        N += cntS[k]; P += posS[k];
        double Jnew = jaccval(N, P, totP);
        acc += 0.5 * (Jprev + Jnew);
        Jprev = Jnew;
    }

    __shared__ double red[TPB];
    red[t] = acc;
    __syncthreads();
    for (int s2 = TPB / 2; s2 > 0; s2 >>= 1) {
        if (t < s2) red[t] += red[t + s2];
        __syncthreads();
    }
    if (t == 0) {
        double loss_c = red[0] / (double)NB;   // × bucket width
        atomicAdd(out0, (float)(loss_c / (double)NCLS));
    }
}

extern "C" void kernel_launch(void* const* d_in, const int* in_sizes, int n_in,
                              void* d_out, int out_size, void* d_ws, size_t ws_size,
                              hipStream_t stream)
{
    const float* logits = (const float*)d_in[0];
    const int*   label  = (const int*)d_in[1];
    float* out = (float*)d_out;

    unsigned int* partial = (unsigned int*)d_ws;

    // 576 blocks -> 2048 px/block (u16-safe); shrink if workspace is small
    int nblk = 576;
    if ((size_t)nblk * HSZ * sizeof(unsigned int) > ws_size) {
        nblk = (int)(ws_size / ((size_t)HSZ * sizeof(unsigned int)));
        if (nblk < 19) nblk = 19;   // still u16-safe (<= 65535 px/block)
    }

    hipMemsetAsync(d_out, 0, sizeof(float), stream);

    softmax_err_hist<<<nblk, TPB, 0, stream>>>(logits, label, out + 1, partial, nblk);
    lovasz_scan<<<NCLS, TPB, 0, stream>>>(partial, nblk, out);
}

// Round 3
// 199.617 us; speedup vs baseline: 6.5761x; 1.3858x over previous
//
#include <hip/hip_runtime.h>

// Problem constants (N,C,H,W) = (8,19,384,384)
#define NCLS 19
#define HW   147456            // 384*384
#define MPIX 1179648           // 8*384*384
#define NB   512               // histogram buckets per class (LDS-resident)
#define TPB  512               // hist block threads (8 waves)
#define NBLK 288               // hist blocks: 288*512*8 == MPIX exactly
#define HSZ  (NCLS * NB)       // 9728 packed u32 words per block histogram
#define RGROUPS 8              // reduce: groups along partial axis
#define RPER  (NBLK / RGROUPS) // 36 partials per group
#define WBLK  ((HSZ + 255) / 256)  // 38 word-blocks of 256 threads

// Kernel A: per-pixel softmax -> errs output + per-block LDS histogram.
// hist[c][k] packs cnt in low 16 bits, pos in high 16 bits (per-block pixel
// count == 4096 < 65536, no overflow).
__global__ void __launch_bounds__(TPB) softmax_err_hist(
    const float* __restrict__ logits,
    const int* __restrict__ label,
    float* __restrict__ errs,              // [C, M]
    unsigned int* __restrict__ partial)    // [NBLK][HSZ]
{
    __shared__ unsigned int hist[HSZ];     // 38,912 B -> 4 blocks/CU, 32 waves
    const int tid = threadIdx.x;
    const int b = blockIdx.x;

    for (int i = tid; i < HSZ; i += TPB) hist[i] = 0u;
    __syncthreads();

    for (int m = b * TPB + tid; m < MPIX; m += NBLK * TPB) {
        int n = m / HW;
        int base = m + n * (NCLS - 1) * HW;     // == n*C*HW + (m - n*HW)

        float v[NCLS];
        float mx = -1e30f;
#pragma unroll
        for (int c = 0; c < NCLS; ++c) {
            float x = logits[base + c * HW];
            v[c] = x;
            mx = fmaxf(mx, x);
        }
        float s = 0.f;
#pragma unroll
        for (int c = 0; c < NCLS; ++c) {
            float e = __expf(v[c] - mx);
            v[c] = e;
            s += e;
        }
        float inv = 1.0f / s;
        int lbl = label[m];
#pragma unroll
        for (int c = 0; c < NCLS; ++c) {
            float p = v[c] * inv;
            float err = (c == lbl) ? (1.0f - p) : p;
            errs[c * MPIX + m] = err;
            int k = (int)(err * (float)NB);
            k = min(k, NB - 1);
            k = max(k, 0);
            unsigned int add = 1u + ((c == lbl) ? 65536u : 0u);
            atomicAdd(&hist[c * NB + k], add);
        }
    }
    __syncthreads();

    // non-atomic coalesced flush to this block's private slice
    unsigned int* dst = partial + (size_t)b * HSZ;
    for (int i = tid; i < HSZ; i += TPB) dst[i] = hist[i];
}

// Kernel R: reduce NBLK packed partials -> unpacked u32 cnt32/pos32.
// grid = WBLK * RGROUPS blocks of 256; thread owns one (c,k) word per group.
__global__ void __launch_bounds__(256) reduce_hist(
    const unsigned int* __restrict__ partial,   // [NBLK][HSZ]
    unsigned int* __restrict__ cnt32,           // [HSZ]
    unsigned int* __restrict__ pos32)           // [HSZ]
{
    int g = blockIdx.x / WBLK;
    int wb = blockIdx.x % WBLK;
    int i = wb * 256 + threadIdx.x;
    if (i >= HSZ) return;

    unsigned int sc = 0, sp = 0;
    const unsigned int* src = partial + (size_t)(g * RPER) * HSZ + i;
#pragma unroll 4
    for (int b = 0; b < RPER; ++b) {
        unsigned int w = src[(size_t)b * HSZ];
        sc += w & 0xFFFFu;
        sp += w >> 16;
    }
    atomicAdd(&cnt32[i], sc);
    atomicAdd(&pos32[i], sp);
}

__device__ __forceinline__ double jaccval(unsigned int n, unsigned int p, unsigned int npos)
{
    // J = 1 - (npos - p) / (npos + n - p); define 0/0 -> 0
    unsigned int denom = (npos - p) + n;
    if (denom == 0u) return 0.0;
    return 1.0 - (double)(npos - p) / (double)denom;
}

// Kernel B: one block per class. Suffix-scan + trapezoid integrate.
__global__ void __launch_bounds__(256) lovasz_scan(
    const unsigned int* __restrict__ cnt32,
    const unsigned int* __restrict__ pos32,
    float* __restrict__ out0)
{
    const int c = blockIdx.x;
    const int t = threadIdx.x;

    __shared__ unsigned int cntS[NB], posS[NB];
    cntS[t]       = cnt32[c * NB + t];
    cntS[t + 256] = cnt32[c * NB + t + 256];
    posS[t]       = pos32[c * NB + t];
    posS[t + 256] = pos32[c * NB + t + 256];
    __syncthreads();

    // per-thread chunk (2 buckets: 2t, 2t+1) sums
    unsigned int sc = cntS[2 * t] + cntS[2 * t + 1];
    unsigned int sp = posS[2 * t] + posS[2 * t + 1];

    __shared__ unsigned int scS[256], spS[256];
    scS[t] = sc; spS[t] = sp;
    __syncthreads();

    // suffix-exclusive counts (buckets above my chunk) + total positives
    unsigned int N = 0, P = 0, totP = 0;
    for (int u = 0; u < 256; ++u) {
        totP += spS[u];
        if (u > t) { N += scS[u]; P += spS[u]; }
    }

    // walk my 2 buckets from the top, trapezoid integrate
    double acc = 0.0;
    double Jprev = jaccval(N, P, totP);
    for (int k = 2 * t + 1; k >= 2 * t; --k) {
        N += cntS[k]; P += posS[k];
        double Jnew = jaccval(N, P, totP);
        acc += 0.5 * (Jprev + Jnew);
        Jprev = Jnew;
    }

    __shared__ double red[256];
    red[t] = acc;
    __syncthreads();
    for (int s2 = 128; s2 > 0; s2 >>= 1) {
        if (t < s2) red[t] += red[t + s2];
        __syncthreads();
    }
    if (t == 0) {
        double loss_c = red[0] / (double)NB;   // × bucket width
        atomicAdd(out0, (float)(loss_c / (double)NCLS));
    }
}

extern "C" void kernel_launch(void* const* d_in, const int* in_sizes, int n_in,
                              void* d_out, int out_size, void* d_ws, size_t ws_size,
                              hipStream_t stream)
{
    const float* logits = (const float*)d_in[0];
    const int*   label  = (const int*)d_in[1];
    float* out = (float*)d_out;

    // ws layout: [cnt32 HSZ][pos32 HSZ][partial NBLK*HSZ]
    unsigned int* cnt32   = (unsigned int*)d_ws;
    unsigned int* pos32   = cnt32 + HSZ;
    unsigned int* partial = pos32 + HSZ;

    hipMemsetAsync(d_ws, 0, (size_t)2 * HSZ * sizeof(unsigned int), stream);
    hipMemsetAsync(d_out, 0, sizeof(float), stream);

    softmax_err_hist<<<NBLK, TPB, 0, stream>>>(logits, label, out + 1, partial);
    reduce_hist<<<WBLK * RGROUPS, 256, 0, stream>>>(partial, cnt32, pos32);
    lovasz_scan<<<NCLS, 256, 0, stream>>>(cnt32, pos32, out);
}